// Round 1
// baseline (5993.724 us; speedup 1.0000x reference)
//
#include <hip/hip_runtime.h>

#define HH 128
#define WW 128
#define HWP (HH*WW)
#define NC 64
#define NB 2
#define NN 5
#define OFFC 144

// out[b, center=2] = x_center
__global__ __launch_bounds__(256) void copy_center_k(const float* __restrict__ xc,
                                                     float* __restrict__ out) {
    int idx = blockIdx.x * 256 + threadIdx.x;
    const int total = NB * 3 * HWP;
    if (idx >= total) return;
    int b = idx / (3 * HWP);
    int r = idx - b * 3 * HWP;
    out[(size_t)((b * NN + 2) * 3) * HWP + r] = xc[idx];
}

// Direct 3x3 SAME conv, NCHW. 16x16 spatial tile per block (256 threads, 1 px/thread).
// MODE 0: in = feature buffer (jl-strided), out = feature buffer.
// MODE 1: input = concat(ref, supp) read straight from pf.
// MODE 2: out = d_out at [b, frame, co, :, :] (rec conv).
// Weights are read with block-uniform indices -> compiler emits s_load (scalar pipe).
template<int CIN, int NCO, int MODE>
__global__ __launch_bounds__(256) void conv3x3_k(
    const float* __restrict__ in, const float* __restrict__ pf,
    const float* __restrict__ w, const float* __restrict__ bias,
    float* __restrict__ out, int job0)
{
    constexpr int CB = 4;                 // channels staged per barrier round
    const int jl = blockIdx.y;
    const int jg = job0 + jl;
    const int b = jg & 1, fi = jg >> 1;
    const int frame = fi + (fi >= 2 ? 1 : 0);   // center = 2
    const int co0 = blockIdx.z * NCO;
    const int Ct  = gridDim.z * NCO;      // total Cout of this conv
    const int tile = blockIdx.x;          // 8x8 tiles of 16x16
    const int ty0 = (tile >> 3) << 4, tx0 = (tile & 7) << 4;
    const int tid = threadIdx.x;
    const int tx = tid & 15, ty = tid >> 4;

    const float* srcA;
    const float* srcB = nullptr;
    if (MODE == 1) {
        srcA = pf + (size_t)((b * NN + 2) * NC) * HWP;       // ref
        srcB = pf + (size_t)((b * NN + frame) * NC) * HWP;   // supp
    } else {
        srcA = in + (size_t)jl * CIN * HWP;
    }

    __shared__ float lds[CB * 342];       // per channel: 18 rows, pitch 19
    float acc[NCO];
#pragma unroll
    for (int o = 0; o < NCO; ++o) acc[o] = 0.f;

    for (int cb = 0; cb < CIN; cb += CB) {
        __syncthreads();
        // stage CB channels of the 18x18 halo tile
        for (int e = tid; e < CB * 324; e += 256) {
            int c = e / 324;
            int r = e - c * 324;
            int iy = r / 18, ix = r - iy * 18;
            int gy = ty0 - 1 + iy, gx = tx0 - 1 + ix;
            int ci = cb + c;
            const float* s;
            if (MODE == 1)
                s = (ci < NC) ? (srcA + (size_t)ci * HWP) : (srcB + (size_t)(ci - NC) * HWP);
            else
                s = srcA + (size_t)ci * HWP;
            float v = 0.f;
            if (gy >= 0 && gy < HH && gx >= 0 && gx < WW) v = s[gy * WW + gx];
            lds[c * 342 + iy * 19 + ix] = v;
        }
        __syncthreads();
        for (int c = 0; c < CB; ++c) {
            float t[9];
#pragma unroll
            for (int dy = 0; dy < 3; ++dy)
#pragma unroll
                for (int dx = 0; dx < 3; ++dx)
                    t[dy * 3 + dx] = lds[c * 342 + (ty + dy) * 19 + (tx + dx)];
            int ci = cb + c;
            const float* wp = w + ((size_t)co0 * CIN + ci) * 9;
#pragma unroll
            for (int o = 0; o < NCO; ++o) {
                const float* wo = wp + (size_t)o * CIN * 9;
#pragma unroll
                for (int kk = 0; kk < 9; ++kk)
                    acc[o] = fmaf(wo[kk], t[kk], acc[o]);
            }
        }
    }
    const int oy = ty0 + ty, ox = tx0 + tx;
#pragma unroll
    for (int o = 0; o < NCO; ++o) {
        float v = acc[o] + bias[co0 + o];
        if (MODE == 2)
            out[((size_t)(b * NN + frame) * 3 + (co0 + o)) * HWP + oy * WW + ox] = v;
        else
            out[((size_t)jl * Ct + co0 + o) * HWP + oy * WW + ox] = v;
    }
}

// Deformable conv (v1, DG=8, Cg=8, 3x3). Block = 256 thr = 8x8 px tile x 4 waves.
// Wave q computes out channels [16q, 16q+16). Per group g:
//  phase A: 576 (px,kk) tasks -> bilinear samples for 8 cg into LDS (pitch 73).
//  phase B: 72 LDS reads + 1152 fma per thread, weights via uniform s_load.
__global__ __launch_bounds__(256) void deform_k(
    const float* __restrict__ in, const float* __restrict__ off,
    const float* __restrict__ w, const float* __restrict__ bias,
    float* __restrict__ out, int job0, int supp_mode, const float* __restrict__ pf)
{
    const int jl = blockIdx.y;
    const int jg = job0 + jl;
    const int b = jg & 1, fi = jg >> 1;
    const int frame = fi + (fi >= 2 ? 1 : 0);
    const int tile = blockIdx.x;          // 16x16 tiles of 8x8
    const int ty0 = (tile >> 4) << 3, tx0 = (tile & 15) << 3;
    const int tid = threadIdx.x;
    const int p = tid & 63;
    const int q = __builtin_amdgcn_readfirstlane(tid >> 6);  // wave-uniform co-group

    const float* ibase = supp_mode ? (pf + (size_t)((b * NN + frame) * NC) * HWP)
                                   : (in + (size_t)jl * NC * HWP);
    const float* obase = off + (size_t)jl * OFFC * HWP;

    __shared__ float samp[64 * 73];
    float acc[16];
#pragma unroll
    for (int o = 0; o < 16; ++o) acc[o] = 0.f;

    for (int g = 0; g < 8; ++g) {
        __syncthreads();
        // ---- phase A: bilinear sampling into LDS ----
        for (int tk = tid; tk < 576; tk += 256) {
            int kk = tk >> 6;             // 0..8
            int pp = tk & 63;
            int yy = ty0 + (pp >> 3), xx = tx0 + (pp & 7);
            int ch = (g * 9 + kk) * 2;    // offset channel layout: (g, kk, {y,x})
            float oyv = obase[(size_t)ch * HWP + yy * WW + xx];
            float oxv = obase[(size_t)(ch + 1) * HWP + yy * WW + xx];
            float py = (float)(yy + (kk / 3) - 1) + oyv;
            float px = (float)(xx + (kk % 3) - 1) + oxv;
            float fy = floorf(py), fx = floorf(px);
            float wy = py - fy, wx = px - fx;
            int y0 = (int)fy, x0 = (int)fx;
            int y1 = y0 + 1, x1 = x0 + 1;
            float m00 = (y0 >= 0 && y0 < HH && x0 >= 0 && x0 < WW) ? 1.f : 0.f;
            float m01 = (y0 >= 0 && y0 < HH && x1 >= 0 && x1 < WW) ? 1.f : 0.f;
            float m10 = (y1 >= 0 && y1 < HH && x0 >= 0 && x0 < WW) ? 1.f : 0.f;
            float m11 = (y1 >= 0 && y1 < HH && x1 >= 0 && x1 < WW) ? 1.f : 0.f;
            float w00 = (1.f - wy) * (1.f - wx) * m00;
            float w01 = (1.f - wy) * wx * m01;
            float w10 = wy * (1.f - wx) * m10;
            float w11 = wy * wx * m11;
            int cy0 = min(max(y0, 0), HH - 1), cy1 = min(max(y1, 0), HH - 1);
            int cx0 = min(max(x0, 0), WW - 1), cx1 = min(max(x1, 0), WW - 1);
            int a00 = cy0 * WW + cx0, a01 = cy0 * WW + cx1;
            int a10 = cy1 * WW + cx0, a11 = cy1 * WW + cx1;
            const float* ib = ibase + (size_t)(g * 8) * HWP;
#pragma unroll
            for (int cg = 0; cg < 8; ++cg) {
                const float* ip = ib + (size_t)cg * HWP;
                float s = ip[a00] * w00;
                s = fmaf(ip[a01], w01, s);
                s = fmaf(ip[a10], w10, s);
                s = fmaf(ip[a11], w11, s);
                samp[pp * 73 + cg * 9 + kk] = s;
            }
        }
        __syncthreads();
        // ---- phase B: contraction (16 couts per wave) ----
#pragma unroll
        for (int cg = 0; cg < 8; ++cg) {
            int cin = g * 8 + cg;
            const float* wrow = w + ((size_t)(q * 16) * NC + cin) * 9;
#pragma unroll
            for (int kk = 0; kk < 9; ++kk) {
                float s = samp[p * 73 + cg * 9 + kk];
#pragma unroll
                for (int o = 0; o < 16; ++o)
                    acc[o] = fmaf(wrow[(size_t)o * NC * 9 + kk], s, acc[o]);
            }
        }
    }
    const int oy = ty0 + (p >> 3), ox = tx0 + (p & 7);
#pragma unroll
    for (int o = 0; o < 16; ++o) {
        int co = q * 16 + o;
        out[((size_t)jl * NC + co) * HWP + oy * WW + ox] = acc[o] + bias[co];
    }
}

extern "C" void kernel_launch(void* const* d_in, const int* in_sizes, int n_in,
                              void* d_out, int out_size, void* d_ws, size_t ws_size,
                              hipStream_t stream)
{
    const float* pf    = (const float*)d_in[0];
    const float* xc    = (const float*)d_in[1];
    const float* cr_w  = (const float*)d_in[2];
    const float* cr_b  = (const float*)d_in[3];
    const float* ow[4] = {(const float*)d_in[4],  (const float*)d_in[8],
                          (const float*)d_in[12], (const float*)d_in[16]};
    const float* ob[4] = {(const float*)d_in[5],  (const float*)d_in[9],
                          (const float*)d_in[13], (const float*)d_in[17]};
    const float* dw[4] = {(const float*)d_in[6],  (const float*)d_in[10],
                          (const float*)d_in[14], (const float*)d_in[18]};
    const float* db[4] = {(const float*)d_in[7],  (const float*)d_in[11],
                          (const float*)d_in[15], (const float*)d_in[19]};
    const float* rec_w = (const float*)d_in[20];
    const float* rec_b = (const float*)d_in[21];
    float* out = (float*)d_out;

    // Workspace: A (64ch) + B (64ch) + O (144ch) per job; chunk jobs if ws is small.
    const size_t per_job = (size_t)(NC + NC + OFFC) * HWP * sizeof(float);  // ~17.8 MB
    int JC = 8;
    while (JC > 1 && per_job * (size_t)JC > ws_size) JC >>= 1;
    float* A  = (float*)d_ws;
    float* Bb = A  + (size_t)JC * NC * HWP;
    float* O  = Bb + (size_t)JC * NC * HWP;

    copy_center_k<<<dim3((NB * 3 * HWP + 255) / 256), 256, 0, stream>>>(xc, out);

    for (int job0 = 0; job0 < 8; job0 += JC) {
        dim3 blk(256);
        // fea1 = cr_conv(concat(ref, supp))
        conv3x3_k<128, 64, 1><<<dim3(64, JC, 1), blk, 0, stream>>>(nullptr, pf, cr_w, cr_b, A, job0);
        // off1(fea1); fea2 = deform(fea1)
        conv3x3_k<64, 48, 0><<<dim3(64, JC, 3), blk, 0, stream>>>(A, nullptr, ow[0], ob[0], O, job0);
        deform_k<<<dim3(256, JC), blk, 0, stream>>>(A, O, dw[0], db[0], Bb, job0, 0, pf);
        // off2(fea2); fea3 = deform(fea2)
        conv3x3_k<64, 48, 0><<<dim3(64, JC, 3), blk, 0, stream>>>(Bb, nullptr, ow[1], ob[1], O, job0);
        deform_k<<<dim3(256, JC), blk, 0, stream>>>(Bb, O, dw[1], db[1], A, job0, 0, pf);
        // off3(fea3); fea4 = deform(supp)
        conv3x3_k<64, 48, 0><<<dim3(64, JC, 3), blk, 0, stream>>>(A, nullptr, ow[2], ob[2], O, job0);
        deform_k<<<dim3(256, JC), blk, 0, stream>>>(nullptr, O, dw[2], db[2], Bb, job0, 1, pf);
        // off4(fea4); aligned = deform(fea4)
        conv3x3_k<64, 48, 0><<<dim3(64, JC, 3), blk, 0, stream>>>(Bb, nullptr, ow[3], ob[3], O, job0);
        deform_k<<<dim3(256, JC), blk, 0, stream>>>(Bb, O, dw[3], db[3], A, job0, 0, pf);
        // out[b, frame] = rec_conv(aligned)
        conv3x3_k<64, 3, 2><<<dim3(64, JC, 1), blk, 0, stream>>>(A, nullptr, rec_w, rec_b, out, job0);
    }
}